// Round 1
// baseline (202.892 us; speedup 1.0000x reference)
//
#include <hip/hip_runtime.h>
#include <math.h>

// Problem constants
#define B_   128
#define T_   1024
#define D_   256
#define L_   512

__device__ __forceinline__ float sigmoidf_(float x) {
    return 1.f / (1.f + __expf(-x));
}
__device__ __forceinline__ float tanhf_(float x) {
    x = fminf(fmaxf(x, -15.f), 15.f);
    float e = __expf(2.f * x);
    return (e - 1.f) / (e + 1.f);
}
__device__ __forceinline__ float waveReduceSum(float v) {
    #pragma unroll
    for (int o = 32; o > 0; o >>= 1) v += __shfl_xor(v, o, 64);
    return v;
}
__device__ __forceinline__ float waveReduceMax(float v) {
    #pragma unroll
    for (int o = 32; o > 0; o >>= 1) v = fmaxf(v, __shfl_xor(v, o, 64));
    return v;
}

// ---------------------------------------------------------------------------
// K1: prenet + GRU cell + q = attn_h @ attn_W.T        (2 batches per block)
// ---------------------------------------------------------------------------
__global__ __launch_bounds__(256) void k1_prenet_gru_q(
    const float* __restrict__ prenet_in, const float* __restrict__ attn_hidden,
    const float* __restrict__ context_vec,
    const float* __restrict__ fc1_W, const float* __restrict__ fc1_b,
    const float* __restrict__ fc2_W, const float* __restrict__ fc2_b,
    const float* __restrict__ gru_Wih, const float* __restrict__ gru_Whh,
    const float* __restrict__ gru_bih, const float* __restrict__ gru_bhh,
    const float* __restrict__ attn_W,
    float* __restrict__ attn_h_out, float* __restrict__ q_out)
{
    const int t = threadIdx.x;
    const int b0 = blockIdx.x * 2;

    __shared__ __align__(16) float pin[2][80];
    __shared__ __align__(16) float xin[2][384];   // [context_vec(256) | prenet_out(128)]
    __shared__ __align__(16) float p1[2][256];
    __shared__ __align__(16) float gi[2][768];
    __shared__ __align__(16) float gh[2][768];
    __shared__ __align__(16) float hprev[2][256];
    __shared__ __align__(16) float ahn[2][256];

    if (t < 80) {
        pin[0][t] = prenet_in[b0 * 80 + t];
        pin[1][t] = prenet_in[(b0 + 1) * 80 + t];
    }
    xin[0][t]   = context_vec[b0 * 256 + t];
    xin[1][t]   = context_vec[(b0 + 1) * 256 + t];
    hprev[0][t] = attn_hidden[b0 * 256 + t];
    hprev[1][t] = attn_hidden[(b0 + 1) * 256 + t];
    __syncthreads();

    // fc1: 256 outputs, K=80
    {
        float a0 = fc1_b[t], a1 = a0;
        const float* w = fc1_W + t * 80;
        #pragma unroll 8
        for (int k = 0; k < 80; k++) {
            float wv = w[k];
            a0 += pin[0][k] * wv;
            a1 += pin[1][k] * wv;
        }
        p1[0][t] = fmaxf(a0, 0.f);
        p1[1][t] = fmaxf(a1, 0.f);
    }
    __syncthreads();

    // fc2: 128 outputs, K=256
    if (t < 128) {
        float a0 = fc2_b[t], a1 = a0;
        const float4* w  = (const float4*)(fc2_W + t * 256);
        const float4* x0 = (const float4*)p1[0];
        const float4* x1 = (const float4*)p1[1];
        #pragma unroll 8
        for (int k = 0; k < 64; k++) {
            float4 wv = w[k], v0 = x0[k], v1 = x1[k];
            a0 += v0.x * wv.x + v0.y * wv.y + v0.z * wv.z + v0.w * wv.w;
            a1 += v1.x * wv.x + v1.y * wv.y + v1.z * wv.z + v1.w * wv.w;
        }
        xin[0][256 + t] = fmaxf(a0, 0.f);
        xin[1][256 + t] = fmaxf(a1, 0.f);
    }
    __syncthreads();

    // gi: 768 outputs, K=384
    for (int j = t; j < 768; j += 256) {
        float a0 = gru_bih[j], a1 = a0;
        const float4* w  = (const float4*)(gru_Wih + j * 384);
        const float4* x0 = (const float4*)xin[0];
        const float4* x1 = (const float4*)xin[1];
        #pragma unroll 8
        for (int k = 0; k < 96; k++) {
            float4 wv = w[k], v0 = x0[k], v1 = x1[k];
            a0 += v0.x * wv.x + v0.y * wv.y + v0.z * wv.z + v0.w * wv.w;
            a1 += v1.x * wv.x + v1.y * wv.y + v1.z * wv.z + v1.w * wv.w;
        }
        gi[0][j] = a0; gi[1][j] = a1;
    }
    // gh: 768 outputs, K=256
    for (int j = t; j < 768; j += 256) {
        float a0 = gru_bhh[j], a1 = a0;
        const float4* w  = (const float4*)(gru_Whh + j * 256);
        const float4* x0 = (const float4*)hprev[0];
        const float4* x1 = (const float4*)hprev[1];
        #pragma unroll 8
        for (int k = 0; k < 64; k++) {
            float4 wv = w[k], v0 = x0[k], v1 = x1[k];
            a0 += v0.x * wv.x + v0.y * wv.y + v0.z * wv.z + v0.w * wv.w;
            a1 += v1.x * wv.x + v1.y * wv.y + v1.z * wv.z + v1.w * wv.w;
        }
        gh[0][j] = a0; gh[1][j] = a1;
    }
    __syncthreads();

    // GRU gates
    #pragma unroll
    for (int bb = 0; bb < 2; bb++) {
        float rg = sigmoidf_(gi[bb][t] + gh[bb][t]);
        float zg = sigmoidf_(gi[bb][256 + t] + gh[bb][256 + t]);
        float ng = tanhf_(gi[bb][512 + t] + rg * gh[bb][512 + t]);
        float h  = (1.f - zg) * ng + zg * hprev[bb][t];
        ahn[bb][t] = h;
        attn_h_out[(b0 + bb) * 256 + t] = h;
    }
    __syncthreads();

    // q = attn_h @ attn_W.T
    {
        float a0 = 0.f, a1 = 0.f;
        const float4* w  = (const float4*)(attn_W + t * 256);
        const float4* x0 = (const float4*)ahn[0];
        const float4* x1 = (const float4*)ahn[1];
        #pragma unroll 8
        for (int k = 0; k < 64; k++) {
            float4 wv = w[k], v0 = x0[k], v1 = x1[k];
            a0 += v0.x * wv.x + v0.y * wv.y + v0.z * wv.z + v0.w * wv.w;
            a1 += v1.x * wv.x + v1.y * wv.y + v1.z * wv.z + v1.w * wv.w;
        }
        q_out[b0 * 256 + t]       = a0;
        q_out[(b0 + 1) * 256 + t] = a1;
    }
}

// ---------------------------------------------------------------------------
// K2: u[b,t] = sum_d tanh(proj[b,t,d] + q[b,d]) * v[d]
// grid = B * 8 chunks of 128 t;  one t per wave iteration
// ---------------------------------------------------------------------------
__global__ __launch_bounds__(256) void k2_scores(
    const float* __restrict__ enc_proj, const float* __restrict__ q,
    const float* __restrict__ v, float* __restrict__ u)
{
    const int b     = blockIdx.x >> 3;
    const int chunk = blockIdx.x & 7;
    const int lane  = threadIdx.x & 63;
    const int wv    = threadIdx.x >> 6;   // 0..3

    float4 qv = ((const float4*)(q + b * 256))[lane];
    float4 vv = ((const float4*)v)[lane];
    const float4* base = (const float4*)enc_proj + ((size_t)(b * T_ + chunk * 128)) * 64;

    #pragma unroll 4
    for (int i = 0; i < 32; i++) {
        int t = wv * 32 + i;
        float4 pj = base[(size_t)t * 64 + lane];
        float s = tanhf_(pj.x + qv.x) * vv.x + tanhf_(pj.y + qv.y) * vv.y
                + tanhf_(pj.z + qv.z) * vv.z + tanhf_(pj.w + qv.w) * vv.w;
        s = waveReduceSum(s);
        if (lane == 0) u[b * T_ + chunk * 128 + t] = s;
    }
}

// ---------------------------------------------------------------------------
// K3: per-batch softmax stats (max, sumexp) over T
// ---------------------------------------------------------------------------
__global__ __launch_bounds__(256) void k3_stats(
    const float* __restrict__ u, float* __restrict__ m_out, float* __restrict__ s_out)
{
    const int b = blockIdx.x, t = threadIdx.x;
    const int lane = t & 63, wv = t >> 6;
    const float* ub = u + b * T_;
    float v0 = ub[t], v1 = ub[t + 256], v2 = ub[t + 512], v3 = ub[t + 768];

    float a = fmaxf(fmaxf(v0, v1), fmaxf(v2, v3));
    a = waveReduceMax(a);
    __shared__ float redm[4], reds[4], mb[1];
    if (lane == 0) redm[wv] = a;
    __syncthreads();
    float m = fmaxf(fmaxf(redm[0], redm[1]), fmaxf(redm[2], redm[3]));

    float s = __expf(v0 - m) + __expf(v1 - m) + __expf(v2 - m) + __expf(v3 - m);
    s = waveReduceSum(s);
    if (lane == 0) reds[wv] = s;
    __syncthreads();
    if (t == 0) {
        m_out[b] = m;
        s_out[b] = reds[0] + reds[1] + reds[2] + reds[3];
    }
    (void)mb;
}

// ---------------------------------------------------------------------------
// K4: normalized scores + context partial.  block = (b, half of T)
// 512 threads = 8 groups x 64 lanes; lane owns 4 d's (float4)
// ---------------------------------------------------------------------------
__global__ __launch_bounds__(512) void k4_context(
    const float* __restrict__ enc, const float* __restrict__ u,
    const float* __restrict__ m_in, const float* __restrict__ s_in,
    float* __restrict__ scores_out, float* __restrict__ ctx_part)
{
    const int b = blockIdx.x >> 1, h = blockIdx.x & 1;
    const int tid = threadIdx.x;
    __shared__ float p_lds[512];
    __shared__ __align__(16) float4 red[8][64];

    float m = m_in[b], inv = 1.f / s_in[b];
    {
        int t = h * 512 + tid;
        float p = __expf(u[b * T_ + t] - m) * inv;
        scores_out[b * T_ + t] = p;
        p_lds[tid] = p;
    }
    __syncthreads();

    const int lane = tid & 63, g = tid >> 6;
    const float4* base = (const float4*)enc + ((size_t)(b * T_ + h * 512 + g * 64)) * 64;
    float4 acc = {0.f, 0.f, 0.f, 0.f};
    #pragma unroll 8
    for (int tt = 0; tt < 64; tt++) {
        float4 e = base[(size_t)tt * 64 + lane];
        float pv = p_lds[g * 64 + tt];
        acc.x += e.x * pv; acc.y += e.y * pv; acc.z += e.z * pv; acc.w += e.w * pv;
    }
    red[g][lane] = acc;
    __syncthreads();
    if (tid < 64) {
        float4 s = {0.f, 0.f, 0.f, 0.f};
        #pragma unroll
        for (int gg = 0; gg < 8; gg++) {
            float4 a = red[gg][tid];
            s.x += a.x; s.y += a.y; s.z += a.z; s.w += a.w;
        }
        ((float4*)ctx_part)[(size_t)(h * 128 + b) * 64 + tid] = s;
    }
}

// ---------------------------------------------------------------------------
// K5: context = part0 + part1 ; build concat1 = [context | attn_h]
// ---------------------------------------------------------------------------
__global__ __launch_bounds__(256) void k5_combine(
    const float* __restrict__ ctx_part, const float* __restrict__ attn_h,
    float* __restrict__ context_out, float* __restrict__ concat1)
{
    const int b = blockIdx.x, d = threadIdx.x;
    float c = ctx_part[b * 256 + d] + ctx_part[(128 + b) * 256 + d];
    context_out[b * 256 + d] = c;
    concat1[b * 512 + d] = c;
    concat1[b * 512 + 256 + d] = attn_h[b * 256 + d];
}

// ---------------------------------------------------------------------------
// GEMM: part[z][m][n] = A_seg[m][k0:k0+KSZ] @ W_seg[n][k0:k0+KSZ]^T
// tile 64m x 64n, microtile 4x4, K per segment = 512, row stride = 512
// grid = (N/64, 2, nseg*ksPerSeg)
// ---------------------------------------------------------------------------
__global__ __launch_bounds__(256) void gemm512_splitk(
    const float* __restrict__ A1, const float* __restrict__ W1,
    const float* __restrict__ A2, const float* __restrict__ W2,
    float* __restrict__ part, int N, int ksPerSeg)
{
    const int n0 = blockIdx.x * 64, m0 = blockIdx.y * 64;
    const int seg = blockIdx.z / ksPerSeg, ls = blockIdx.z % ksPerSeg;
    const int KSZ = 512 / ksPerSeg;
    const float* A = seg ? A2 : A1;
    const float* W = seg ? W2 : W1;
    const int k0 = ls * KSZ;

    __shared__ __align__(16) float As[32][68];
    __shared__ __align__(16) float Ws[32][68];

    const int tid = threadIdx.x;
    const int tm = tid & 15, tn = tid >> 4;
    const int rs = tid >> 3, qs = tid & 7;

    float acc[4][4] = {};

    for (int kt = 0; kt < KSZ; kt += 32) {
        #pragma unroll
        for (int it = 0; it < 2; it++) {
            int r = rs + it * 32;
            float4 av = *(const float4*)(A + (size_t)(m0 + r) * 512 + k0 + kt + qs * 4);
            As[qs * 4 + 0][r] = av.x; As[qs * 4 + 1][r] = av.y;
            As[qs * 4 + 2][r] = av.z; As[qs * 4 + 3][r] = av.w;
            float4 wv = *(const float4*)(W + (size_t)(n0 + r) * 512 + k0 + kt + qs * 4);
            Ws[qs * 4 + 0][r] = wv.x; Ws[qs * 4 + 1][r] = wv.y;
            Ws[qs * 4 + 2][r] = wv.z; Ws[qs * 4 + 3][r] = wv.w;
        }
        __syncthreads();
        #pragma unroll
        for (int kk = 0; kk < 32; kk++) {
            float4 a = *(const float4*)&As[kk][tm * 4];
            float4 w = *(const float4*)&Ws[kk][tn * 4];
            acc[0][0] += a.x * w.x; acc[0][1] += a.x * w.y; acc[0][2] += a.x * w.z; acc[0][3] += a.x * w.w;
            acc[1][0] += a.y * w.x; acc[1][1] += a.y * w.y; acc[1][2] += a.y * w.z; acc[1][3] += a.y * w.w;
            acc[2][0] += a.z * w.x; acc[2][1] += a.z * w.y; acc[2][2] += a.z * w.z; acc[2][3] += a.z * w.w;
            acc[3][0] += a.w * w.x; acc[3][1] += a.w * w.y; acc[3][2] += a.w * w.z; acc[3][3] += a.w * w.w;
        }
        __syncthreads();
    }

    float* pb = part + ((size_t)blockIdx.z * 128 + m0) * N + n0;
    #pragma unroll
    for (int i = 0; i < 4; i++) {
        float4 o = {acc[i][0], acc[i][1], acc[i][2], acc[i][3]};
        *(float4*)(pb + (size_t)(tm * 4 + i) * N + tn * 4) = o;
    }
}

// ---------------------------------------------------------------------------
// E_rnn: x = sum_z part[z] + bias     (N=512, 4 slices)
// ---------------------------------------------------------------------------
__global__ __launch_bounds__(256) void e_rnn(
    const float* __restrict__ part, const float* __restrict__ bias,
    float* __restrict__ x)
{
    const int idx = blockIdx.x * 256 + threadIdx.x;   // < 128*512
    const int n = idx & 511;
    float a = bias[n];
    #pragma unroll
    for (int z = 0; z < 4; z++) a += part[(size_t)z * 65536 + idx];
    x[idx] = a;
}

// ---------------------------------------------------------------------------
// E_lstm: gate reduce (4 slices, N=2048) + LSTM cell + x_new = x_prev + h
// ---------------------------------------------------------------------------
__global__ __launch_bounds__(256) void e_lstm(
    const float* __restrict__ part,
    const float* __restrict__ bih, const float* __restrict__ bhh,
    const float* __restrict__ c_prev, const float* __restrict__ x_prev,
    float* __restrict__ h_out, float* __restrict__ c_out, float* __restrict__ x_new)
{
    const int idx = blockIdx.x * 256 + threadIdx.x;   // < 128*512
    const int bb = idx >> 9, j = idx & 511;
    float gi = bih[j] + bhh[j];
    float gf = bih[512 + j] + bhh[512 + j];
    float gg = bih[1024 + j] + bhh[1024 + j];
    float go = bih[1536 + j] + bhh[1536 + j];
    #pragma unroll
    for (int z = 0; z < 4; z++) {
        const float* p = part + ((size_t)z * 128 + bb) * 2048;
        gi += p[j]; gf += p[512 + j]; gg += p[1024 + j]; go += p[1536 + j];
    }
    float c = sigmoidf_(gf) * c_prev[idx] + sigmoidf_(gi) * tanhf_(gg);
    float h = sigmoidf_(go) * tanhf_(c);
    h_out[idx] = h;
    c_out[idx] = c;
    x_new[idx] = x_prev[idx] + h;
}

// ---------------------------------------------------------------------------
// K_mel: mels[b, m, rr] = x3[b] . mel_W[m*20+rr]   for rr < r
// ---------------------------------------------------------------------------
__global__ __launch_bounds__(256) void k_mel(
    const float* __restrict__ x3, const float* __restrict__ mel_W,
    const int* __restrict__ r_ptr, float* __restrict__ mels)
{
    const int b = blockIdx.x;
    __shared__ __align__(16) float xs[512];
    xs[threadIdx.x] = x3[b * 512 + threadIdx.x];
    xs[256 + threadIdx.x] = x3[b * 512 + 256 + threadIdx.x];
    __syncthreads();
    const int r = r_ptr[0];
    const int tot = 80 * r;
    for (int n = threadIdx.x; n < tot; n += 256) {
        int m = n / r, rr = n % r;
        const float4* w  = (const float4*)(mel_W + (size_t)(m * 20 + rr) * 512);
        const float4* xv = (const float4*)xs;
        float a = 0.f;
        #pragma unroll 8
        for (int k = 0; k < 128; k++) {
            float4 wv = w[k], vv = xv[k];
            a += wv.x * vv.x + wv.y * vv.y + wv.z * vv.z + wv.w * vv.w;
        }
        mels[(size_t)b * tot + n] = a;
    }
}

// ---------------------------------------------------------------------------
extern "C" void kernel_launch(void* const* d_in, const int* in_sizes, int n_in,
                              void* d_out, int out_size, void* d_ws, size_t ws_size,
                              hipStream_t stream)
{
    const float* enc   = (const float*)d_in[0];
    const float* encp  = (const float*)d_in[1];
    const float* pre   = (const float*)d_in[2];
    const float* ah_in = (const float*)d_in[3];
    const float* r1h   = (const float*)d_in[4];
    const float* r2h   = (const float*)d_in[5];
    const float* r1c   = (const float*)d_in[6];
    const float* r2c   = (const float*)d_in[7];
    const float* cvec  = (const float*)d_in[8];
    const float* fc1W  = (const float*)d_in[9];
    const float* fc1b  = (const float*)d_in[10];
    const float* fc2W  = (const float*)d_in[11];
    const float* fc2b  = (const float*)d_in[12];
    const float* attnW = (const float*)d_in[13];
    const float* attnv = (const float*)d_in[14];
    const float* gWih  = (const float*)d_in[15];
    const float* gWhh  = (const float*)d_in[16];
    const float* gbih  = (const float*)d_in[17];
    const float* gbhh  = (const float*)d_in[18];
    const float* rinW  = (const float*)d_in[19];
    const float* rinb  = (const float*)d_in[20];
    const float* l1Wih = (const float*)d_in[21];
    const float* l1Whh = (const float*)d_in[22];
    const float* l1bih = (const float*)d_in[23];
    const float* l1bhh = (const float*)d_in[24];
    const float* l2Wih = (const float*)d_in[25];
    const float* l2Whh = (const float*)d_in[26];
    const float* l2bih = (const float*)d_in[27];
    const float* l2bhh = (const float*)d_in[28];
    const float* melW  = (const float*)d_in[29];
    const int*   rp    = (const int*)d_in[30];

    float* out = (float*)d_out;
    // output tuple layout (flat float32, reference return order)
    float* o_mels  = out + 0;        // 128*80*2   = 20480
    float* o_scor  = out + 20480;    // 128*1*1024 = 131072
    float* o_attnh = out + 151552;   // 128*256
    float* o_r1h   = out + 184320;   // 128*512
    float* o_r2h   = out + 249856;
    float* o_r1c   = out + 315392;
    float* o_r2c   = out + 380928;
    float* o_ctx   = out + 446464;   // 128*256

    float* ws    = (float*)d_ws;
    float* w_q    = ws + 0;          // 32768
    float* w_u    = ws + 32768;      // 131072
    float* w_m    = ws + 163840;     // 128
    float* w_s    = ws + 163968;     // 128
    float* w_ctxp = ws + 164096;     // 65536
    float* w_cat1 = ws + 229632;     // 65536
    float* w_x    = ws + 295168;     // 65536
    float* w_x2   = ws + 360704;     // 65536
    float* w_x3   = ws + 426240;     // 65536
    float* w_part = ws + 491776;     // up to 4*128*2048 = 1048576

    hipLaunchKernelGGL(k1_prenet_gru_q, dim3(64), dim3(256), 0, stream,
                       pre, ah_in, cvec, fc1W, fc1b, fc2W, fc2b,
                       gWih, gWhh, gbih, gbhh, attnW, o_attnh, w_q);

    hipLaunchKernelGGL(k2_scores, dim3(1024), dim3(256), 0, stream,
                       encp, w_q, attnv, w_u);

    hipLaunchKernelGGL(k3_stats, dim3(128), dim3(256), 0, stream, w_u, w_m, w_s);

    hipLaunchKernelGGL(k4_context, dim3(256), dim3(512), 0, stream,
                       enc, w_u, w_m, w_s, o_scor, w_ctxp);

    hipLaunchKernelGGL(k5_combine, dim3(128), dim3(256), 0, stream,
                       w_ctxp, o_attnh, o_ctx, w_cat1);

    // rnn_in: x = concat1 @ rnn_in_W^T + b    (1 segment, K=512, 4 k-slices)
    hipLaunchKernelGGL(gemm512_splitk, dim3(8, 2, 4), dim3(256), 0, stream,
                       w_cat1, rinW, w_cat1, rinW, w_part, 512, 4);
    hipLaunchKernelGGL(e_rnn, dim3(256), dim3(256), 0, stream, w_part, rinb, w_x);

    // LSTM 1 (2 segments of K=512, 2 k-slices each -> 4 partials)
    hipLaunchKernelGGL(gemm512_splitk, dim3(32, 2, 4), dim3(256), 0, stream,
                       w_x, l1Wih, r1h, l1Whh, w_part, 2048, 2);
    hipLaunchKernelGGL(e_lstm, dim3(256), dim3(256), 0, stream,
                       w_part, l1bih, l1bhh, r1c, w_x, o_r1h, o_r1c, w_x2);

    // LSTM 2
    hipLaunchKernelGGL(gemm512_splitk, dim3(32, 2, 4), dim3(256), 0, stream,
                       w_x2, l2Wih, r2h, l2Whh, w_part, 2048, 2);
    hipLaunchKernelGGL(e_lstm, dim3(256), dim3(256), 0, stream,
                       w_part, l2bih, l2bhh, r2c, w_x2, o_r2h, o_r2c, w_x3);

    hipLaunchKernelGGL(k_mel, dim3(128), dim3(256), 0, stream,
                       w_x3, melW, rp, o_mels);
}

// Round 2
// 174.712 us; speedup vs baseline: 1.1613x; 1.1613x over previous
//
#include <hip/hip_runtime.h>
#include <math.h>

// Problem constants
#define B_   128
#define T_   1024
#define D_   256
#define L_   512

__device__ __forceinline__ float sigmoidf_(float x) {
    return 1.f / (1.f + __expf(-x));
}
__device__ __forceinline__ float tanhf_(float x) {
    x = fminf(fmaxf(x, -15.f), 15.f);
    float e = __expf(2.f * x);
    return (e - 1.f) / (e + 1.f);
}
__device__ __forceinline__ float waveReduceSum(float v) {
    #pragma unroll
    for (int o = 32; o > 0; o >>= 1) v += __shfl_xor(v, o, 64);
    return v;
}
__device__ __forceinline__ float waveReduceMax(float v) {
    #pragma unroll
    for (int o = 32; o > 0; o >>= 1) v = fmaxf(v, __shfl_xor(v, o, 64));
    return v;
}

// ---------------------------------------------------------------------------
// K1a: prenet per batch.  grid=128, block=256
//   p2[b][0:128] = relu(fc2(relu(fc1(prenet_in[b]))))
// ---------------------------------------------------------------------------
__global__ __launch_bounds__(256) void k1a_prenet(
    const float* __restrict__ prenet_in,
    const float* __restrict__ fc1_W, const float* __restrict__ fc1_b,
    const float* __restrict__ fc2_W, const float* __restrict__ fc2_b,
    float* __restrict__ p2_out)
{
    const int b = blockIdx.x, t = threadIdx.x;
    __shared__ __align__(16) float pin[80];
    __shared__ __align__(16) float p1[256];

    if (t < 80) pin[t] = prenet_in[b * 80 + t];
    __syncthreads();

    // fc1: 256 outputs, K=80
    {
        float a = fc1_b[t];
        const float4* w  = (const float4*)(fc1_W + t * 80);
        const float4* xv = (const float4*)pin;
        #pragma unroll
        for (int k = 0; k < 20; k++) {
            float4 wv = w[k], v = xv[k];
            a += v.x * wv.x + v.y * wv.y + v.z * wv.z + v.w * wv.w;
        }
        p1[t] = fmaxf(a, 0.f);
    }
    __syncthreads();

    // fc2: 128 outputs, K=256
    if (t < 128) {
        float a = fc2_b[t];
        const float4* w  = (const float4*)(fc2_W + t * 256);
        const float4* xv = (const float4*)p1;
        #pragma unroll 8
        for (int k = 0; k < 64; k++) {
            float4 wv = w[k], v = xv[k];
            a += v.x * wv.x + v.y * wv.y + v.z * wv.z + v.w * wv.w;
        }
        p2_out[b * 128 + t] = fmaxf(a, 0.f);
    }
}

// ---------------------------------------------------------------------------
// K1b: GRU gate GEMVs.  gi[b][j] (K=384 over [cvec|p2]), gh[b][j] (K=256).
// grid = (3 j-tiles, 64 batch-pairs), block = 256.  2 batches per weight row.
// ---------------------------------------------------------------------------
__global__ __launch_bounds__(256) void k1b_gru_gemv(
    const float* __restrict__ context_vec, const float* __restrict__ p2,
    const float* __restrict__ attn_hidden,
    const float* __restrict__ gru_Wih, const float* __restrict__ gru_Whh,
    const float* __restrict__ gru_bih, const float* __restrict__ gru_bhh,
    float* __restrict__ gi_out, float* __restrict__ gh_out)
{
    const int t = threadIdx.x;
    const int j = blockIdx.x * 256 + t;
    const int b0 = blockIdx.y * 2;

    __shared__ __align__(16) float xs[2][384];
    __shared__ __align__(16) float hs[2][256];

    for (int i = t; i < 768; i += 256) {
        int bb = i / 384, k = i % 384;
        xs[bb][k] = (k < 256) ? context_vec[(b0 + bb) * 256 + k]
                              : p2[(b0 + bb) * 128 + (k - 256)];
    }
    for (int i = t; i < 512; i += 256) {
        hs[i / 256][i % 256] = attn_hidden[(b0 + i / 256) * 256 + (i % 256)];
    }
    __syncthreads();

    // gi: K=384
    {
        float a0 = gru_bih[j], a1 = a0;
        const float4* w  = (const float4*)(gru_Wih + (size_t)j * 384);
        const float4* x0 = (const float4*)xs[0];
        const float4* x1 = (const float4*)xs[1];
        #pragma unroll 8
        for (int k = 0; k < 96; k++) {
            float4 wv = w[k], v0 = x0[k], v1 = x1[k];
            a0 += v0.x * wv.x + v0.y * wv.y + v0.z * wv.z + v0.w * wv.w;
            a1 += v1.x * wv.x + v1.y * wv.y + v1.z * wv.z + v1.w * wv.w;
        }
        gi_out[(size_t)(b0 + 0) * 768 + j] = a0;
        gi_out[(size_t)(b0 + 1) * 768 + j] = a1;
    }
    // gh: K=256
    {
        float a0 = gru_bhh[j], a1 = a0;
        const float4* w  = (const float4*)(gru_Whh + (size_t)j * 256);
        const float4* x0 = (const float4*)hs[0];
        const float4* x1 = (const float4*)hs[1];
        #pragma unroll 8
        for (int k = 0; k < 64; k++) {
            float4 wv = w[k], v0 = x0[k], v1 = x1[k];
            a0 += v0.x * wv.x + v0.y * wv.y + v0.z * wv.z + v0.w * wv.w;
            a1 += v1.x * wv.x + v1.y * wv.y + v1.z * wv.z + v1.w * wv.w;
        }
        gh_out[(size_t)(b0 + 0) * 768 + j] = a0;
        gh_out[(size_t)(b0 + 1) * 768 + j] = a1;
    }
}

// ---------------------------------------------------------------------------
// K1c: GRU gates + q = attn_h @ attn_W.T.   grid=128 (per batch), block=256
// ---------------------------------------------------------------------------
__global__ __launch_bounds__(256) void k1c_gates_q(
    const float* __restrict__ gi, const float* __restrict__ gh,
    const float* __restrict__ attn_hidden, const float* __restrict__ attn_W,
    float* __restrict__ attn_h_out, float* __restrict__ q_out)
{
    const int b = blockIdx.x, t = threadIdx.x;
    __shared__ __align__(16) float ahn[256];

    {
        float hp = attn_hidden[b * 256 + t];
        float rg = sigmoidf_(gi[(size_t)b * 768 + t]       + gh[(size_t)b * 768 + t]);
        float zg = sigmoidf_(gi[(size_t)b * 768 + 256 + t] + gh[(size_t)b * 768 + 256 + t]);
        float ng = tanhf_(gi[(size_t)b * 768 + 512 + t] + rg * gh[(size_t)b * 768 + 512 + t]);
        float h  = (1.f - zg) * ng + zg * hp;
        ahn[t] = h;
        attn_h_out[b * 256 + t] = h;
    }
    __syncthreads();

    {
        float a = 0.f;
        const float4* w  = (const float4*)(attn_W + (size_t)t * 256);
        const float4* xv = (const float4*)ahn;
        #pragma unroll 8
        for (int k = 0; k < 64; k++) {
            float4 wv = w[k], v = xv[k];
            a += v.x * wv.x + v.y * wv.y + v.z * wv.z + v.w * wv.w;
        }
        q_out[b * 256 + t] = a;
    }
}

// ---------------------------------------------------------------------------
// K2: u[b,t] = sum_d tanh(proj[b,t,d] + q[b,d]) * v[d]
// grid = B * 8 chunks of 128 t;  one t per wave iteration
// ---------------------------------------------------------------------------
__global__ __launch_bounds__(256) void k2_scores(
    const float* __restrict__ enc_proj, const float* __restrict__ q,
    const float* __restrict__ v, float* __restrict__ u)
{
    const int b     = blockIdx.x >> 3;
    const int chunk = blockIdx.x & 7;
    const int lane  = threadIdx.x & 63;
    const int wv    = threadIdx.x >> 6;   // 0..3

    float4 qv = ((const float4*)(q + b * 256))[lane];
    float4 vv = ((const float4*)v)[lane];
    const float4* base = (const float4*)enc_proj + ((size_t)(b * T_ + chunk * 128)) * 64;

    #pragma unroll 4
    for (int i = 0; i < 32; i++) {
        int t = wv * 32 + i;
        float4 pj = base[(size_t)t * 64 + lane];
        float s = tanhf_(pj.x + qv.x) * vv.x + tanhf_(pj.y + qv.y) * vv.y
                + tanhf_(pj.z + qv.z) * vv.z + tanhf_(pj.w + qv.w) * vv.w;
        s = waveReduceSum(s);
        if (lane == 0) u[b * T_ + chunk * 128 + t] = s;
    }
}

// ---------------------------------------------------------------------------
// K3: per-batch softmax stats (max, sumexp) over T
// ---------------------------------------------------------------------------
__global__ __launch_bounds__(256) void k3_stats(
    const float* __restrict__ u, float* __restrict__ m_out, float* __restrict__ s_out)
{
    const int b = blockIdx.x, t = threadIdx.x;
    const int lane = t & 63, wv = t >> 6;
    const float* ub = u + b * T_;
    float v0 = ub[t], v1 = ub[t + 256], v2 = ub[t + 512], v3 = ub[t + 768];

    float a = fmaxf(fmaxf(v0, v1), fmaxf(v2, v3));
    a = waveReduceMax(a);
    __shared__ float redm[4], reds[4];
    if (lane == 0) redm[wv] = a;
    __syncthreads();
    float m = fmaxf(fmaxf(redm[0], redm[1]), fmaxf(redm[2], redm[3]));

    float s = __expf(v0 - m) + __expf(v1 - m) + __expf(v2 - m) + __expf(v3 - m);
    s = waveReduceSum(s);
    if (lane == 0) reds[wv] = s;
    __syncthreads();
    if (t == 0) {
        m_out[b] = m;
        s_out[b] = reds[0] + reds[1] + reds[2] + reds[3];
    }
}

// ---------------------------------------------------------------------------
// K4: normalized scores + context partial.  block = (b, half of T)
// 512 threads = 8 groups x 64 lanes; lane owns 4 d's (float4)
// ---------------------------------------------------------------------------
__global__ __launch_bounds__(512) void k4_context(
    const float* __restrict__ enc, const float* __restrict__ u,
    const float* __restrict__ m_in, const float* __restrict__ s_in,
    float* __restrict__ scores_out, float* __restrict__ ctx_part)
{
    const int b = blockIdx.x >> 1, h = blockIdx.x & 1;
    const int tid = threadIdx.x;
    __shared__ float p_lds[512];
    __shared__ __align__(16) float4 red[8][64];

    float m = m_in[b], inv = 1.f / s_in[b];
    {
        int t = h * 512 + tid;
        float p = __expf(u[b * T_ + t] - m) * inv;
        scores_out[b * T_ + t] = p;
        p_lds[tid] = p;
    }
    __syncthreads();

    const int lane = tid & 63, g = tid >> 6;
    const float4* base = (const float4*)enc + ((size_t)(b * T_ + h * 512 + g * 64)) * 64;
    float4 acc = {0.f, 0.f, 0.f, 0.f};
    #pragma unroll 8
    for (int tt = 0; tt < 64; tt++) {
        float4 e = base[(size_t)tt * 64 + lane];
        float pv = p_lds[g * 64 + tt];
        acc.x += e.x * pv; acc.y += e.y * pv; acc.z += e.z * pv; acc.w += e.w * pv;
    }
    red[g][lane] = acc;
    __syncthreads();
    if (tid < 64) {
        float4 s = {0.f, 0.f, 0.f, 0.f};
        #pragma unroll
        for (int gg = 0; gg < 8; gg++) {
            float4 a = red[gg][tid];
            s.x += a.x; s.y += a.y; s.z += a.z; s.w += a.w;
        }
        ((float4*)ctx_part)[(size_t)(h * 128 + b) * 64 + tid] = s;
    }
}

// ---------------------------------------------------------------------------
// K5: context = part0 + part1 ; build concat1 = [context | attn_h]
// ---------------------------------------------------------------------------
__global__ __launch_bounds__(256) void k5_combine(
    const float* __restrict__ ctx_part, const float* __restrict__ attn_h,
    float* __restrict__ context_out, float* __restrict__ concat1)
{
    const int b = blockIdx.x, d = threadIdx.x;
    float c = ctx_part[b * 256 + d] + ctx_part[(128 + b) * 256 + d];
    context_out[b * 256 + d] = c;
    concat1[b * 512 + d] = c;
    concat1[b * 512 + 256 + d] = attn_h[b * 256 + d];
}

// ---------------------------------------------------------------------------
// GEMM: part[z][m][n] = A_seg[m][k0:k0+KSZ] @ W_seg[n][k0:k0+KSZ]^T
// tile 64m x 64n, microtile 4x4, K per segment = 512, row stride = 512
// grid = (N/64, 2, nseg*ksPerSeg)
// ---------------------------------------------------------------------------
__global__ __launch_bounds__(256) void gemm512_splitk(
    const float* __restrict__ A1, const float* __restrict__ W1,
    const float* __restrict__ A2, const float* __restrict__ W2,
    float* __restrict__ part, int N, int ksPerSeg)
{
    const int n0 = blockIdx.x * 64, m0 = blockIdx.y * 64;
    const int seg = blockIdx.z / ksPerSeg, ls = blockIdx.z % ksPerSeg;
    const int KSZ = 512 / ksPerSeg;
    const float* A = seg ? A2 : A1;
    const float* W = seg ? W2 : W1;
    const int k0 = ls * KSZ;

    __shared__ __align__(16) float As[32][68];
    __shared__ __align__(16) float Ws[32][68];

    const int tid = threadIdx.x;
    const int tm = tid & 15, tn = tid >> 4;
    const int rs = tid >> 3, qs = tid & 7;

    float acc[4][4] = {};

    for (int kt = 0; kt < KSZ; kt += 32) {
        #pragma unroll
        for (int it = 0; it < 2; it++) {
            int r = rs + it * 32;
            float4 av = *(const float4*)(A + (size_t)(m0 + r) * 512 + k0 + kt + qs * 4);
            As[qs * 4 + 0][r] = av.x; As[qs * 4 + 1][r] = av.y;
            As[qs * 4 + 2][r] = av.z; As[qs * 4 + 3][r] = av.w;
            float4 wv = *(const float4*)(W + (size_t)(n0 + r) * 512 + k0 + kt + qs * 4);
            Ws[qs * 4 + 0][r] = wv.x; Ws[qs * 4 + 1][r] = wv.y;
            Ws[qs * 4 + 2][r] = wv.z; Ws[qs * 4 + 3][r] = wv.w;
        }
        __syncthreads();
        #pragma unroll
        for (int kk = 0; kk < 32; kk++) {
            float4 a = *(const float4*)&As[kk][tm * 4];
            float4 w = *(const float4*)&Ws[kk][tn * 4];
            acc[0][0] += a.x * w.x; acc[0][1] += a.x * w.y; acc[0][2] += a.x * w.z; acc[0][3] += a.x * w.w;
            acc[1][0] += a.y * w.x; acc[1][1] += a.y * w.y; acc[1][2] += a.y * w.z; acc[1][3] += a.y * w.w;
            acc[2][0] += a.z * w.x; acc[2][1] += a.z * w.y; acc[2][2] += a.z * w.z; acc[2][3] += a.z * w.w;
            acc[3][0] += a.w * w.x; acc[3][1] += a.w * w.y; acc[3][2] += a.w * w.z; acc[3][3] += a.w * w.w;
        }
        __syncthreads();
    }

    float* pb = part + ((size_t)blockIdx.z * 128 + m0) * N + n0;
    #pragma unroll
    for (int i = 0; i < 4; i++) {
        float4 o = {acc[i][0], acc[i][1], acc[i][2], acc[i][3]};
        *(float4*)(pb + (size_t)(tm * 4 + i) * N + tn * 4) = o;
    }
}

// ---------------------------------------------------------------------------
// E_rnn: x = sum_z part[z] + bias     (N=512, 4 slices)
// ---------------------------------------------------------------------------
__global__ __launch_bounds__(256) void e_rnn(
    const float* __restrict__ part, const float* __restrict__ bias,
    float* __restrict__ x)
{
    const int idx = blockIdx.x * 256 + threadIdx.x;   // < 128*512
    const int n = idx & 511;
    float a = bias[n];
    #pragma unroll
    for (int z = 0; z < 4; z++) a += part[(size_t)z * 65536 + idx];
    x[idx] = a;
}

// ---------------------------------------------------------------------------
// E_lstm: gate reduce (4 slices, N=2048) + LSTM cell + x_new = x_prev + h
// ---------------------------------------------------------------------------
__global__ __launch_bounds__(256) void e_lstm(
    const float* __restrict__ part,
    const float* __restrict__ bih, const float* __restrict__ bhh,
    const float* __restrict__ c_prev, const float* __restrict__ x_prev,
    float* __restrict__ h_out, float* __restrict__ c_out, float* __restrict__ x_new)
{
    const int idx = blockIdx.x * 256 + threadIdx.x;   // < 128*512
    const int bb = idx >> 9, j = idx & 511;
    float gi = bih[j] + bhh[j];
    float gf = bih[512 + j] + bhh[512 + j];
    float gg = bih[1024 + j] + bhh[1024 + j];
    float go = bih[1536 + j] + bhh[1536 + j];
    #pragma unroll
    for (int z = 0; z < 4; z++) {
        const float* p = part + ((size_t)z * 128 + bb) * 2048;
        gi += p[j]; gf += p[512 + j]; gg += p[1024 + j]; go += p[1536 + j];
    }
    float c = sigmoidf_(gf) * c_prev[idx] + sigmoidf_(gi) * tanhf_(gg);
    float h = sigmoidf_(go) * tanhf_(c);
    h_out[idx] = h;
    c_out[idx] = c;
    x_new[idx] = x_prev[idx] + h;
}

// ---------------------------------------------------------------------------
// K_mel: mels[b, m, rr] = x3[b] . mel_W[m*20+rr]   for rr < r
// ---------------------------------------------------------------------------
__global__ __launch_bounds__(256) void k_mel(
    const float* __restrict__ x3, const float* __restrict__ mel_W,
    const int* __restrict__ r_ptr, float* __restrict__ mels)
{
    const int b = blockIdx.x;
    __shared__ __align__(16) float xs[512];
    xs[threadIdx.x] = x3[b * 512 + threadIdx.x];
    xs[256 + threadIdx.x] = x3[b * 512 + 256 + threadIdx.x];
    __syncthreads();
    const int r = r_ptr[0];
    const int tot = 80 * r;
    for (int n = threadIdx.x; n < tot; n += 256) {
        int m = n / r, rr = n % r;
        const float4* w  = (const float4*)(mel_W + (size_t)(m * 20 + rr) * 512);
        const float4* xv = (const float4*)xs;
        float a = 0.f;
        #pragma unroll 8
        for (int k = 0; k < 128; k++) {
            float4 wv = w[k], vv = xv[k];
            a += wv.x * vv.x + wv.y * vv.y + wv.z * vv.z + wv.w * vv.w;
        }
        mels[(size_t)b * tot + n] = a;
    }
}

// ---------------------------------------------------------------------------
extern "C" void kernel_launch(void* const* d_in, const int* in_sizes, int n_in,
                              void* d_out, int out_size, void* d_ws, size_t ws_size,
                              hipStream_t stream)
{
    const float* enc   = (const float*)d_in[0];
    const float* encp  = (const float*)d_in[1];
    const float* pre   = (const float*)d_in[2];
    const float* ah_in = (const float*)d_in[3];
    const float* r1h   = (const float*)d_in[4];
    const float* r2h   = (const float*)d_in[5];
    const float* r1c   = (const float*)d_in[6];
    const float* r2c   = (const float*)d_in[7];
    const float* cvec  = (const float*)d_in[8];
    const float* fc1W  = (const float*)d_in[9];
    const float* fc1b  = (const float*)d_in[10];
    const float* fc2W  = (const float*)d_in[11];
    const float* fc2b  = (const float*)d_in[12];
    const float* attnW = (const float*)d_in[13];
    const float* attnv = (const float*)d_in[14];
    const float* gWih  = (const float*)d_in[15];
    const float* gWhh  = (const float*)d_in[16];
    const float* gbih  = (const float*)d_in[17];
    const float* gbhh  = (const float*)d_in[18];
    const float* rinW  = (const float*)d_in[19];
    const float* rinb  = (const float*)d_in[20];
    const float* l1Wih = (const float*)d_in[21];
    const float* l1Whh = (const float*)d_in[22];
    const float* l1bih = (const float*)d_in[23];
    const float* l1bhh = (const float*)d_in[24];
    const float* l2Wih = (const float*)d_in[25];
    const float* l2Whh = (const float*)d_in[26];
    const float* l2bih = (const float*)d_in[27];
    const float* l2bhh = (const float*)d_in[28];
    const float* melW  = (const float*)d_in[29];
    const int*   rp    = (const int*)d_in[30];

    float* out = (float*)d_out;
    // output tuple layout (flat float32, reference return order)
    float* o_mels  = out + 0;        // 128*80*2   = 20480
    float* o_scor  = out + 20480;    // 128*1*1024 = 131072
    float* o_attnh = out + 151552;   // 128*256
    float* o_r1h   = out + 184320;   // 128*512
    float* o_r2h   = out + 249856;
    float* o_r1c   = out + 315392;
    float* o_r2c   = out + 380928;
    float* o_ctx   = out + 446464;   // 128*256

    float* ws    = (float*)d_ws;
    float* w_q    = ws + 0;          // 32768
    float* w_u    = ws + 32768;      // 131072
    float* w_m    = ws + 163840;     // 128
    float* w_s    = ws + 163968;     // 128
    float* w_ctxp = ws + 164096;     // 65536
    float* w_cat1 = ws + 229632;     // 65536
    float* w_x    = ws + 295168;     // 65536
    float* w_x2   = ws + 360704;     // 65536
    float* w_x3   = ws + 426240;     // 65536
    float* w_part = ws + 491776;     // up to 4*128*2048 = 1048576

    // front-end scratch reuses the w_part region (free until the GEMM phase)
    float* w_p2 = w_part;            // 128*128  = 16384
    float* w_gi = w_part + 16384;    // 128*768  = 98304
    float* w_gh = w_part + 114688;   // 128*768  = 98304

    hipLaunchKernelGGL(k1a_prenet, dim3(128), dim3(256), 0, stream,
                       pre, fc1W, fc1b, fc2W, fc2b, w_p2);

    hipLaunchKernelGGL(k1b_gru_gemv, dim3(3, 64), dim3(256), 0, stream,
                       cvec, w_p2, ah_in, gWih, gWhh, gbih, gbhh, w_gi, w_gh);

    hipLaunchKernelGGL(k1c_gates_q, dim3(128), dim3(256), 0, stream,
                       w_gi, w_gh, ah_in, attnW, o_attnh, w_q);

    hipLaunchKernelGGL(k2_scores, dim3(1024), dim3(256), 0, stream,
                       encp, w_q, attnv, w_u);

    hipLaunchKernelGGL(k3_stats, dim3(128), dim3(256), 0, stream, w_u, w_m, w_s);

    hipLaunchKernelGGL(k4_context, dim3(256), dim3(512), 0, stream,
                       enc, w_u, w_m, w_s, o_scor, w_ctxp);

    hipLaunchKernelGGL(k5_combine, dim3(128), dim3(256), 0, stream,
                       w_ctxp, o_attnh, o_ctx, w_cat1);

    // rnn_in: x = concat1 @ rnn_in_W^T + b    (1 segment, K=512, 4 k-slices)
    hipLaunchKernelGGL(gemm512_splitk, dim3(8, 2, 4), dim3(256), 0, stream,
                       w_cat1, rinW, w_cat1, rinW, w_part, 512, 4);
    hipLaunchKernelGGL(e_rnn, dim3(256), dim3(256), 0, stream, w_part, rinb, w_x);

    // LSTM 1 (2 segments of K=512, 2 k-slices each -> 4 partials)
    hipLaunchKernelGGL(gemm512_splitk, dim3(32, 2, 4), dim3(256), 0, stream,
                       w_x, l1Wih, r1h, l1Whh, w_part, 2048, 2);
    hipLaunchKernelGGL(e_lstm, dim3(256), dim3(256), 0, stream,
                       w_part, l1bih, l1bhh, r1c, w_x, o_r1h, o_r1c, w_x2);

    // LSTM 2
    hipLaunchKernelGGL(gemm512_splitk, dim3(32, 2, 4), dim3(256), 0, stream,
                       w_x2, l2Wih, r2h, l2Whh, w_part, 2048, 2);
    hipLaunchKernelGGL(e_lstm, dim3(256), dim3(256), 0, stream,
                       w_part, l2bih, l2bhh, r2c, w_x2, o_r2h, o_r2c, w_x3);

    hipLaunchKernelGGL(k_mel, dim3(128), dim3(256), 0, stream,
                       w_x3, melW, rp, o_mels);
}